// Round 8
// baseline (165.206 us; speedup 1.0000x reference)
//
#include <hip/hip_runtime.h>
#include <hip/hip_bf16.h>

// GPT-2 attention block. Inputs/outputs fp32; internal bf16 MFMA, fp32 accum.
// B=4, S=1024, D=1024, H=16, hd=64.
//
// R20: gemm_qkv reverted to the R8/R12 128x128 BK=32 core (measured 43 us in
//      the prior session; the 8-phase 256^2 template measured 50.2 at K=1024
//      with 1 block/CU + 75% grid fill). Fused V-transpose epilogue KEPT by
//      reusing the same 16 KB LDS (sA/sB dead post-loop; [64c][128r] halves,
//      XOR swizzle rL^(l16<<3)). LDS stays 16 KB -> occupancy of the measured
//      config. attn (R19 8-wave paired) / prep / gemm_out verbatim.

typedef __bf16 bf16x8 __attribute__((ext_vector_type(8)));
typedef __bf16 bf16x4 __attribute__((ext_vector_type(4)));
typedef float f32x4 __attribute__((ext_vector_type(4)));

__device__ __forceinline__ void load_lds16(const void* g, void* l) {
  __builtin_amdgcn_global_load_lds(
      (const __attribute__((address_space(1))) void*)g,
      (__attribute__((address_space(3))) void*)l, 16, 0, 0);
}

#define BAR8 asm volatile("s_barrier" ::: "memory")

// ---------------- fused prep: transpose w_attn, w_proj; convert x ----------------
__global__ __launch_bounds__(256) void prep(
    const float* __restrict__ x, const float* __restrict__ w_attn,
    const float* __restrict__ w_proj, __bf16* __restrict__ Xb,
    __bf16* __restrict__ WT_attn, __bf16* __restrict__ WT_proj) {
  __shared__ __bf16 tile[32][33];
  const int blk = blockIdx.x;
  const int tid = threadIdx.x;
  if (blk < 4096) {  // transpose (block-uniform branch)
    const float* W;
    __bf16* WT;
    int n0, k0, N;
    if (blk < 3072) {
      W = w_attn; WT = WT_attn; N = 3072;
      n0 = (blk % 96) * 32; k0 = (blk / 96) * 32;
    } else {
      W = w_proj; WT = WT_proj; N = 1024;
      const int t = blk - 3072;
      n0 = (t & 31) * 32; k0 = (t >> 5) * 32;
    }
    const int tx = tid & 31, ty = tid >> 5;
#pragma unroll
    for (int j = 0; j < 32; j += 8)
      tile[ty + j][tx] = (__bf16)W[(size_t)(k0 + ty + j) * N + n0 + tx];
    __syncthreads();
#pragma unroll
    for (int j = 0; j < 32; j += 8)
      WT[(size_t)(n0 + ty + j) * 1024 + k0 + tx] = tile[tx][ty + j];
  } else {  // x -> bf16, 16 elems/thread
    const size_t i = (size_t)(blk - 4096) * 4096 + tid * 16;
    const float4* xp = (const float4*)(x + i);
    float4 a = xp[0], b = xp[1], c = xp[2], d = xp[3];
    bf16x8 o0, o1;
    o0[0] = (__bf16)a.x; o0[1] = (__bf16)a.y; o0[2] = (__bf16)a.z; o0[3] = (__bf16)a.w;
    o0[4] = (__bf16)b.x; o0[5] = (__bf16)b.y; o0[6] = (__bf16)b.z; o0[7] = (__bf16)b.w;
    o1[0] = (__bf16)c.x; o1[1] = (__bf16)c.y; o1[2] = (__bf16)c.z; o1[3] = (__bf16)c.w;
    o1[4] = (__bf16)d.x; o1[5] = (__bf16)d.y; o1[6] = (__bf16)d.z; o1[7] = (__bf16)d.w;
    *(bf16x8*)(Xb + i) = o0;
    *(bf16x8*)(Xb + i + 8) = o1;
  }
}

// ---------------- GEMM1: 128x128 BK=32 core (R8, measured 43us) ----------------
// dim3(24,32), 256 thr, 16 KB LDS. Epilogues: Q/K packed stores (R12);
// V-seg transposes through the SAME 16 KB LDS in two 64-col halves.
__global__ __launch_bounds__(256) void gemm_qkv(
    const __bf16* __restrict__ A, const __bf16* __restrict__ BT,
    const float* __restrict__ bias, __bf16* __restrict__ Qp,
    __bf16* __restrict__ Kp, __bf16* __restrict__ Vt) {
  __shared__ __bf16 smem[8192];  // 16 KB: sA = [0,4096), sB = [4096,8192)
  __bf16* sA = smem;
  __bf16* sB = smem + 4096;
  const int tid = threadIdx.x;
  const int lane = tid & 63;
  const int wave = tid >> 6;
  const int waveM = wave >> 1, waveN = wave & 1;
  const int quad = lane >> 4;
  const int l16 = lane & 15;
  const int rowBase = blockIdx.y * 128;
  const int colBase = blockIdx.x * 128;
  const int rIn = lane >> 2;
  const int sIn = lane & 3;
  const int gc = sIn ^ (rIn & 3) ^ ((rIn >> 2) & 3);
  const int readSlot = quad ^ (l16 & 3) ^ ((l16 >> 2) & 3);
  f32x4 acc[4][4] = {};

  for (int k0 = 0; k0 < 1024; k0 += 32) {
    __syncthreads();
#pragma unroll
    for (int j = 0; j < 2; ++j) {
      const int rb = wave * 32 + j * 16;
      load_lds16(&A[(size_t)(rowBase + rb + rIn) * 1024 + k0 + gc * 8],
                 &sA[rb * 32]);
      load_lds16(&BT[(size_t)(colBase + rb + rIn) * 1024 + k0 + gc * 8],
                 &sB[rb * 32]);
    }
    __syncthreads();
    bf16x8 af[4], bfr[4];
#pragma unroll
    for (int mt = 0; mt < 4; ++mt)
      af[mt] = *(const bf16x8*)(&sA[(waveM * 64 + mt * 16 + l16) * 32 +
                                    readSlot * 8]);
#pragma unroll
    for (int nt = 0; nt < 4; ++nt)
      bfr[nt] = *(const bf16x8*)(&sB[(waveN * 64 + nt * 16 + l16) * 32 +
                                     readSlot * 8]);
#pragma unroll
    for (int mt = 0; mt < 4; ++mt)
#pragma unroll
      for (int nt = 0; nt < 4; ++nt)
        acc[mt][nt] = __builtin_amdgcn_mfma_f32_16x16x32_bf16(
            af[mt], bfr[nt], acc[mt][nt], 0, 0, 0);
  }

  const int seg = colBase >> 10;  // 0=Q 1=K 2=V (block-uniform)
  if (seg == 2) {
    // ---- V epilogue: transpose through the dead sA/sB space, half-tile at
    // a time ([64 cols][128 rows] = 16 KB). LDS elem addr for (cRel, rL):
    // cRel*128 + (rL ^ (l16<<3)); XOR flips bits 3-6 only -> bf16x4 writes
    // (rL base multiple of 4 within an 8-group) and bf16x8 reads (base
    // multiple of 8) stay contiguous; map bijective per column.
    const int b_ = rowBase >> 10;
    const int s0 = rowBase & 1023;
    __syncthreads();  // all waves done with sA/sB MFMA reads
#pragma unroll
    for (int h = 0; h < 2; ++h) {
      if (waveN == h) {  // this wave's cols are [h*64, h*64+64)
#pragma unroll
        for (int nt = 0; nt < 4; ++nt) {
          const int cRel = nt * 16 + l16;
          const float bv = bias[colBase + h * 64 + cRel];
#pragma unroll
          for (int mt = 0; mt < 4; ++mt) {
            const int rb4 = waveM * 64 + mt * 16 + quad * 4;
            bf16x4 pk;
#pragma unroll
            for (int r = 0; r < 4; ++r) pk[r] = (__bf16)(acc[mt][nt][r] + bv);
            *(bf16x4*)(&smem[cRel * 128 + (rb4 ^ (l16 << 3))]) = pk;
          }
        }
      }
      __syncthreads();
      // 64 cols x 16 chunks = 1024 bf16x8 -> 4 per thread, coalesced stores
#pragma unroll
      for (int p = 0; p < 4; ++p) {
        const int g = p * 256 + tid;
        const int cRel = g >> 4, ch = g & 15;
        bf16x8 v =
            *(const bf16x8*)(&smem[cRel * 128 + ((ch * 8) ^ ((cRel & 15) << 3))]);
        const int cc = (colBase + h * 64 + cRel) & 1023;
        const int bhd = (b_ * 16 + (cc >> 6)) * 64 + (cc & 63);
        *(bf16x8*)(&Vt[(size_t)bhd * 1024 + s0 + ch * 8]) = v;
      }
      __syncthreads();  // before next half overwrites
    }
  } else {
    // ---- Q/K epilogue: packed [bh][s][64]
    __bf16* dst = (seg == 0) ? Qp : Kp;
#pragma unroll
    for (int mt = 0; mt < 4; ++mt) {
      const int row0 = rowBase + waveM * 64 + mt * 16 + quad * 4;
#pragma unroll
      for (int nt = 0; nt < 4; ++nt) {
        const int col = colBase + waveN * 64 + nt * 16 + l16;
        const float bv = bias[col];
        const int cc = col & 1023;
#pragma unroll
        for (int r = 0; r < 4; ++r) {
          const int row = row0 + r;
          const float v = acc[mt][nt][r] + bv;
          const int bh = ((row >> 10) << 4) + (cc >> 6);
          dst[((size_t)bh << 16) + (size_t)(row & 1023) * 64 + (cc & 63)] =
              (__bf16)v;
        }
      }
    }
  }
}

// ---------------- GEMM2: out = A @ WT^T + bias, depth-2 pipelined ----------------
__global__ __launch_bounds__(256) void gemm_out(
    const __bf16* __restrict__ A, const __bf16* __restrict__ BT,
    const float* __restrict__ bias, float* __restrict__ C) {
  __shared__ __bf16 sA[3][128 * 32];  // 24 KB
  __shared__ __bf16 sB[3][128 * 32];  // 24 KB
  const int tid = threadIdx.x;
  const int lane = tid & 63;
  const int wave = tid >> 6;
  const int waveM = wave >> 1, waveN = wave & 1;
  const int quad = lane >> 4;
  const int l16 = lane & 15;
  const int rowBase = blockIdx.x * 128;
  const int colBase = blockIdx.y * 128;
  const int rIn = lane >> 2;
  const int sIn = lane & 3;
  const int gc = sIn ^ (rIn & 3) ^ ((rIn >> 2) & 3);
  const int readSlot = quad ^ (l16 & 3) ^ ((l16 >> 2) & 3);
  f32x4 acc[4][4] = {};

#define GO_STAGE(bi, k0_)                                                      \
  _Pragma("unroll") for (int j_ = 0; j_ < 2; ++j_) {                           \
    const int rb = wave * 32 + j_ * 16;                                        \
    load_lds16(&A[(size_t)(rowBase + rb + rIn) * 1024 + (k0_) + gc * 8],       \
               &sA[bi][rb * 32]);                                              \
    load_lds16(&BT[(size_t)(colBase + rb + rIn) * 1024 + (k0_) + gc * 8],      \
               &sB[bi][rb * 32]);                                              \
  }

  GO_STAGE(0, 0);
  GO_STAGE(1, 32);
  asm volatile("s_waitcnt vmcnt(4)" ::: "memory");  // tile 0 landed
  BAR8;

#pragma unroll
  for (int i = 0; i < 32; ++i) {
    if (i + 2 < 32) { GO_STAGE((i + 2) % 3, (i + 2) * 32); }
    const __bf16* sAc = sA[i % 3];
    const __bf16* sBc = sB[i % 3];
    bf16x8 af[4], bfr[4];
#pragma unroll
    for (int mt = 0; mt < 4; ++mt)
      af[mt] = *(const bf16x8*)(&sAc[(waveM * 64 + mt * 16 + l16) * 32 +
                                     readSlot * 8]);
#pragma unroll
    for (int nt = 0; nt < 4; ++nt)
      bfr[nt] = *(const bf16x8*)(&sBc[(waveN * 64 + nt * 16 + l16) * 32 +
                                      readSlot * 8]);
    __builtin_amdgcn_s_setprio(1);
#pragma unroll
    for (int mt = 0; mt < 4; ++mt)
#pragma unroll
      for (int nt = 0; nt < 4; ++nt)
        acc[mt][nt] = __builtin_amdgcn_mfma_f32_16x16x32_bf16(
            af[mt], bfr[nt], acc[mt][nt], 0, 0, 0);
    __builtin_amdgcn_s_setprio(0);
    if (i + 1 < 32) {
      if (i + 2 < 32) {
        asm volatile("s_waitcnt vmcnt(4)" ::: "memory");  // tile i+1 landed
      } else {
        asm volatile("s_waitcnt vmcnt(0)" ::: "memory");  // drain last stage
      }
      BAR8;
    }
  }

#pragma unroll
  for (int mt = 0; mt < 4; ++mt) {
    const int row = rowBase + waveM * 64 + mt * 16 + quad * 4;
#pragma unroll
    for (int nt = 0; nt < 4; ++nt) {
      const int col = colBase + waveN * 64 + nt * 16 + l16;
      const float bv = bias[col];
#pragma unroll
      for (int r = 0; r < 4; ++r)
        C[(size_t)(row + r) * 1024 + col] = acc[mt][nt][r] + bv;
    }
  }
}

// ---------------- flash attention (R19: paired tiles, 8-wave blocks) ----------
__global__ __launch_bounds__(512, 4) void attn_mfma(
    const __bf16* __restrict__ Qp, const __bf16* __restrict__ Kp,
    const __bf16* __restrict__ VT, __bf16* __restrict__ Aout) {
  __shared__ __bf16 sK[2][128 * 64];  // 32 KB
  __shared__ __bf16 sV[2][64 * 128];  // 32 KB
  __shared__ __bf16 sP[8 * 16 * 64];  // 16 KB, per-wave halved P

  const int tid = threadIdx.x;
  const int lane = tid & 63;
  const int wave = tid >> 6;       // 0..7
  const int wq = wave & 3;         // row-group within my tile
  const int tileSel = wave >> 2;   // 0 = long tile B, 1 = short tile A
  const int quad = lane >> 4;
  const int l16 = lane & 15;
  const int swq = l16 & 7;

  const int bh = blockIdx.x & 63;
  const int pr = blockIdx.x >> 6;  // 0..7
  const int b = bh >> 4, h = bh & 15;
  const int qbB = (15 - pr) * 64, qbA = pr * 64;
  const int ktB_max = (15 - pr) >> 1, ktA_max = pr >> 1;
  const int myQb = tileSel ? qbA : qbB;
  const int myKt = tileSel ? ktA_max : ktB_max;

  const __bf16* Qb = Qp + ((size_t)bh << 16);
  const __bf16* Kb = Kp + ((size_t)bh << 16);
  const __bf16* VTb = VT + (size_t)bh * 64 * 1024;

  bf16x8 qA0, qA1;
  {
    const __bf16* qr = Qb + (size_t)(myQb + wq * 16 + l16) * 64 + quad * 8;
    qA0 = *(const bf16x8*)qr;
    qA1 = *(const bf16x8*)(qr + 32);
  }

  f32x4 O[4] = {};
  float ps[4] = {0.f, 0.f, 0.f, 0.f};
  __bf16* pw = sP + wave * 1024;  // [16][64] per wave

#define ATTN_STAGE(bi, kbase)                                                  \
  _Pragma("unroll") for (int i_ = 0; i_ < 2; ++i_) {                           \
    const int rb = wave * 16 + i_ * 8;                                         \
    load_lds16(Kb + (size_t)((kbase) + rb + (lane >> 3)) * 64 +                \
                   (((lane & 7) ^ ((lane >> 3) & 7)) << 3),                    \
               &sK[bi][rb * 64]);                                              \
  }                                                                            \
  _Pragma("unroll") for (int i_ = 0; i_ < 2; ++i_) {                           \
    const int db = wave * 8 + i_ * 4;                                          \
    const int d = db + (lane >> 4);                                            \
    load_lds16(VTb + (size_t)d * 1024 + (kbase) +                              \
                   (((lane & 15) ^ (d & 7)) << 3),                             \
               &sV[bi][db * 128]);                                             \
  }

  ATTN_STAGE(0, 0);
  asm volatile("s_waitcnt vmcnt(0)" ::: "memory");
  BAR8;

  for (int kt = 0; kt <= ktB_max; ++kt) {
    const int kb = kt * 128;
    const int cur = kt & 1;
    if (kt < ktB_max) { ATTN_STAGE(cur ^ 1, kb + 128); }

    if (kt <= myKt) {  // wave-uniform
      const __bf16* skc = sK[cur];
      const __bf16* svc = sV[cur];

      float sc[8][4];
      __builtin_amdgcn_s_setprio(1);
#pragma unroll
      for (int n = 0; n < 8; ++n) {
        const int key = n * 16 + l16;
        bf16x8 kB0 = *(const bf16x8*)(&skc[key * 64 + ((quad ^ swq) << 3)]);
        bf16x8 kB1 = *(const bf16x8*)(&skc[key * 64 + (((quad + 4) ^ swq) << 3)]);
        f32x4 cacc = {};
        cacc = __builtin_amdgcn_mfma_f32_16x16x32_bf16(qA0, kB0, cacc, 0, 0, 0);
        cacc = __builtin_amdgcn_mfma_f32_16x16x32_bf16(qA1, kB1, cacc, 0, 0, 0);
#pragma unroll
        for (int r = 0; r < 4; ++r) sc[n][r] = cacc[r] * 0.125f;
      }
      __builtin_amdgcn_s_setprio(0);

      if (kt == myKt) {
#pragma unroll
        for (int n = 0; n < 8; ++n) {
          const int kg = kb + n * 16 + l16;
#pragma unroll
          for (int r = 0; r < 4; ++r)
            if (kg > myQb + wq * 16 + quad * 4 + r) sc[n][r] = -1.0e30f;
        }
      }

#pragma unroll
      for (int n = 0; n < 8; ++n)
#pragma unroll
        for (int r = 0; r < 4; ++r) {
          float p = __expf(fminf(sc[n][r], 60.0f));
          sc[n][r] = p;
          ps[r] += p;
        }

      const int kb8 = l16 >> 3, lo = l16 & 7;
#pragma unroll
      for (int hf = 0; hf < 2; ++hf) {
#pragma unroll
        for (int n = 4 * hf; n < 4 * hf + 4; ++n) {
          const int crel = (n - 4 * hf) * 2 + kb8;
#pragma unroll
          for (int r = 0; r < 4; ++r) {
            const int q = quad * 4 + r;
            pw[q * 64 + ((crel ^ (q & 7)) << 3) + lo] = (__bf16)sc[n][r];
          }
        }
        __builtin_amdgcn_s_setprio(1);
#pragma unroll
        for (int cc = 2 * hf; cc < 2 * hf + 2; ++cc) {
          const int crel = (cc - 2 * hf) * 4 + quad;
          bf16x8 pA = *(const bf16x8*)(&pw[l16 * 64 + ((crel ^ swq) << 3)]);
#pragma unroll
          for (int nt = 0; nt < 4; ++nt) {
            bf16x8 vB = *(const bf16x8*)(&svc[(nt * 16 + l16) * 128 +
                                              (((cc * 4 + quad) ^ swq) << 3)]);
            O[nt] = __builtin_amdgcn_mfma_f32_16x16x32_bf16(pA, vB, O[nt], 0, 0, 0);
          }
        }
        __builtin_amdgcn_s_setprio(0);
      }
    }

    if (kt < ktB_max) {
      asm volatile("s_waitcnt vmcnt(0)" ::: "memory");
      BAR8;
    }
  }

  // ---- epilogue
  float inv[4];
#pragma unroll
  for (int r = 0; r < 4; ++r) {
    float pa = ps[r];
    pa += __shfl_xor(pa, 1);
    pa += __shfl_xor(pa, 2);
    pa += __shfl_xor(pa, 4);
    pa += __shfl_xor(pa, 8);
    inv[r] = 1.0f / pa;
  }
#pragma unroll
  for (int nt = 0; nt < 4; ++nt) {
#pragma unroll
    for (int r = 0; r < 4; ++r) {
      const int q = myQb + wq * 16 + quad * 4 + r;
      Aout[((size_t)b * 1024 + q) * 1024 + h * 64 + nt * 16 + l16] =
          (__bf16)(O[nt][r] * inv[r]);
    }
  }
}

// ---------------- launch ----------------
extern "C" void kernel_launch(void* const* d_in, const int* in_sizes, int n_in,
                              void* d_out, int out_size, void* d_ws,
                              size_t ws_size, hipStream_t stream) {
  const float* x      = (const float*)d_in[0];
  const float* w_attn = (const float*)d_in[1];
  const float* b_attn = (const float*)d_in[2];
  const float* w_proj = (const float*)d_in[3];
  const float* b_proj = (const float*)d_in[4];
  float* out = (float*)d_out;

  char* ws = (char*)d_ws;
  __bf16* WT_attn = (__bf16*)(ws);                  //  6 MB
  __bf16* WT_proj = (__bf16*)(ws + 6291456);        //  2 MB
  __bf16* Xb      = (__bf16*)(ws + 8388608);        //  8 MB
  __bf16* Qp      = (__bf16*)(ws + 16777216);       //  8 MB [bh][s][64]
  __bf16* Kp      = (__bf16*)(ws + 25165824);       //  8 MB [bh][s][64]
  __bf16* VT      = (__bf16*)(ws + 33554432);       //  8 MB [bh][d][s]
  __bf16* Aattn   = (__bf16*)(ws + 41943040);       //  8 MB (end 50 MB)

  prep<<<5120, 256, 0, stream>>>(x, w_attn, w_proj, Xb, WT_attn, WT_proj);
  gemm_qkv<<<dim3(24, 32), 256, 0, stream>>>(Xb, WT_attn, b_attn, Qp, Kp, VT);
  attn_mfma<<<512, 512, 0, stream>>>(Qp, Kp, VT, Aattn);
  gemm_out<<<dim3(32, 8), 256, 0, stream>>>(Aattn, WT_proj, b_proj, out);
}

// Round 9
// 161.000 us; speedup vs baseline: 1.0261x; 1.0261x over previous
//
#include <hip/hip_runtime.h>
#include <hip/hip_bf16.h>

// GPT-2 attention block. Inputs/outputs fp32; internal bf16 MFMA, fp32 accum.
// B=4, S=1024, D=1024, H=16, hd=64.
//
// R21: gemm_qkv gets the SAME 3-buffer depth-2 counted-vmcnt pipeline that
//      gemm_out already uses (stage i+2, compute i, wait vmcnt(4) = tile i+1
//      landed; never a full drain in the steady loop). 48 KB LDS, 3 blk/CU.
//      V epilogue transposes through the first 32 KB in ONE pass (buffers
//      0+1 region; last two K-iters read only buffer 2, so no aliasing).
//      attn (R19 8-wave paired) / prep / gemm_out verbatim.

typedef __bf16 bf16x8 __attribute__((ext_vector_type(8)));
typedef __bf16 bf16x4 __attribute__((ext_vector_type(4)));
typedef float f32x4 __attribute__((ext_vector_type(4)));

__device__ __forceinline__ void load_lds16(const void* g, void* l) {
  __builtin_amdgcn_global_load_lds(
      (const __attribute__((address_space(1))) void*)g,
      (__attribute__((address_space(3))) void*)l, 16, 0, 0);
}

#define BAR8 asm volatile("s_barrier" ::: "memory")

// ---------------- fused prep: transpose w_attn, w_proj; convert x ----------------
__global__ __launch_bounds__(256) void prep(
    const float* __restrict__ x, const float* __restrict__ w_attn,
    const float* __restrict__ w_proj, __bf16* __restrict__ Xb,
    __bf16* __restrict__ WT_attn, __bf16* __restrict__ WT_proj) {
  __shared__ __bf16 tile[32][33];
  const int blk = blockIdx.x;
  const int tid = threadIdx.x;
  if (blk < 4096) {  // transpose (block-uniform branch)
    const float* W;
    __bf16* WT;
    int n0, k0, N;
    if (blk < 3072) {
      W = w_attn; WT = WT_attn; N = 3072;
      n0 = (blk % 96) * 32; k0 = (blk / 96) * 32;
    } else {
      W = w_proj; WT = WT_proj; N = 1024;
      const int t = blk - 3072;
      n0 = (t & 31) * 32; k0 = (t >> 5) * 32;
    }
    const int tx = tid & 31, ty = tid >> 5;
#pragma unroll
    for (int j = 0; j < 32; j += 8)
      tile[ty + j][tx] = (__bf16)W[(size_t)(k0 + ty + j) * N + n0 + tx];
    __syncthreads();
#pragma unroll
    for (int j = 0; j < 32; j += 8)
      WT[(size_t)(n0 + ty + j) * 1024 + k0 + tx] = tile[tx][ty + j];
  } else {  // x -> bf16, 16 elems/thread
    const size_t i = (size_t)(blk - 4096) * 4096 + tid * 16;
    const float4* xp = (const float4*)(x + i);
    float4 a = xp[0], b = xp[1], c = xp[2], d = xp[3];
    bf16x8 o0, o1;
    o0[0] = (__bf16)a.x; o0[1] = (__bf16)a.y; o0[2] = (__bf16)a.z; o0[3] = (__bf16)a.w;
    o0[4] = (__bf16)b.x; o0[5] = (__bf16)b.y; o0[6] = (__bf16)b.z; o0[7] = (__bf16)b.w;
    o1[0] = (__bf16)c.x; o1[1] = (__bf16)c.y; o1[2] = (__bf16)c.z; o1[3] = (__bf16)c.w;
    o1[4] = (__bf16)d.x; o1[5] = (__bf16)d.y; o1[6] = (__bf16)d.z; o1[7] = (__bf16)d.w;
    *(bf16x8*)(Xb + i) = o0;
    *(bf16x8*)(Xb + i + 8) = o1;
  }
}

// ---------------- GEMM1: 128x128 BK=32, 3-buffer depth-2 pipeline ----------------
// dim3(24,32), 256 thr, 48 KB LDS (buffer bi at smem+bi*8192: A 4096, B 4096).
// Epilogues: Q/K packed stores; V-seg transposes through smem[0..16384) in
// one pass (region holds buffers 0+1; iters 30/31 read only buffer 2/0 resp.
// -- actually i=30 reads buf 0 BEFORE its trailing barrier, i=31 reads buf 2,
// so after the final barrier writes to [0,16384) race with nothing).
__global__ __launch_bounds__(256) void gemm_qkv(
    const __bf16* __restrict__ A, const __bf16* __restrict__ BT,
    const float* __restrict__ bias, __bf16* __restrict__ Qp,
    __bf16* __restrict__ Kp, __bf16* __restrict__ Vt) {
  __shared__ __bf16 smem[24576];  // 48 KB
  const int tid = threadIdx.x;
  const int lane = tid & 63;
  const int wave = tid >> 6;
  const int waveM = wave >> 1, waveN = wave & 1;
  const int quad = lane >> 4;
  const int l16 = lane & 15;
  const int rowBase = blockIdx.y * 128;
  const int colBase = blockIdx.x * 128;
  const int rIn = lane >> 2;
  const int sIn = lane & 3;
  const int gc = sIn ^ (rIn & 3) ^ ((rIn >> 2) & 3);
  const int readSlot = quad ^ (l16 & 3) ^ ((l16 >> 2) & 3);
  f32x4 acc[4][4] = {};

#define QS_STAGE(bi, k0_)                                                      \
  _Pragma("unroll") for (int j_ = 0; j_ < 2; ++j_) {                           \
    const int rb = wave * 32 + j_ * 16;                                        \
    load_lds16(&A[(size_t)(rowBase + rb + rIn) * 1024 + (k0_) + gc * 8],       \
               smem + (bi)*8192 + rb * 32);                                    \
    load_lds16(&BT[(size_t)(colBase + rb + rIn) * 1024 + (k0_) + gc * 8],      \
               smem + (bi)*8192 + 4096 + rb * 32);                             \
  }

  QS_STAGE(0, 0);
  QS_STAGE(1, 32);
  asm volatile("s_waitcnt vmcnt(4)" ::: "memory");  // tile 0 landed
  BAR8;

#pragma unroll
  for (int i = 0; i < 32; ++i) {
    if (i + 2 < 32) { QS_STAGE((i + 2) % 3, (i + 2) * 32); }
    const __bf16* sAc = smem + (i % 3) * 8192;
    const __bf16* sBc = sAc + 4096;
    bf16x8 af[4], bfr[4];
#pragma unroll
    for (int mt = 0; mt < 4; ++mt)
      af[mt] = *(const bf16x8*)(&sAc[(waveM * 64 + mt * 16 + l16) * 32 +
                                     readSlot * 8]);
#pragma unroll
    for (int nt = 0; nt < 4; ++nt)
      bfr[nt] = *(const bf16x8*)(&sBc[(waveN * 64 + nt * 16 + l16) * 32 +
                                      readSlot * 8]);
    __builtin_amdgcn_s_setprio(1);
#pragma unroll
    for (int mt = 0; mt < 4; ++mt)
#pragma unroll
      for (int nt = 0; nt < 4; ++nt)
        acc[mt][nt] = __builtin_amdgcn_mfma_f32_16x16x32_bf16(
            af[mt], bfr[nt], acc[mt][nt], 0, 0, 0);
    __builtin_amdgcn_s_setprio(0);
    if (i + 1 < 32) {
      if (i + 2 < 32) {
        asm volatile("s_waitcnt vmcnt(4)" ::: "memory");  // tile i+1 landed
      } else {
        asm volatile("s_waitcnt vmcnt(0)" ::: "memory");  // drain last stage
      }
      BAR8;
    }
  }

  const int seg = colBase >> 10;  // 0=Q 1=K 2=V (block-uniform)
  if (seg == 2) {
    // ---- V epilogue: full 128x128 transpose via smem[0..16384).
    // LDS elem addr for (cRel, rL): cRel*128 + (rL ^ ((cRel&15)<<3)); XOR
    // flips bits 3-6 only -> bf16x4 writes / bf16x8 reads stay contiguous,
    // bijective per column. (Same algebra as R20, single pass.)
    const int b_ = rowBase >> 10;
    const int s0 = rowBase & 1023;
    __syncthreads();  // all waves past final K-iter reads of buffers 0/1
#pragma unroll
    for (int nt = 0; nt < 4; ++nt) {
      const int cRel = waveN * 64 + nt * 16 + l16;
      const float bv = bias[colBase + cRel];
#pragma unroll
      for (int mt = 0; mt < 4; ++mt) {
        const int rb4 = waveM * 64 + mt * 16 + quad * 4;
        bf16x4 pk;
#pragma unroll
        for (int r = 0; r < 4; ++r) pk[r] = (__bf16)(acc[mt][nt][r] + bv);
        *(bf16x4*)(&smem[cRel * 128 + (rb4 ^ (l16 << 3))]) = pk;
      }
    }
    __syncthreads();
    // 128 cols x 16 chunks = 2048 bf16x8 -> 8 per thread, coalesced stores
#pragma unroll
    for (int p = 0; p < 8; ++p) {
      const int g = p * 256 + tid;
      const int cRel = g >> 4, ch = g & 15;
      bf16x8 v =
          *(const bf16x8*)(&smem[cRel * 128 + ((ch * 8) ^ ((cRel & 15) << 3))]);
      const int cc = (colBase + cRel) & 1023;
      const int bhd = (b_ * 16 + (cc >> 6)) * 64 + (cc & 63);
      *(bf16x8*)(&Vt[(size_t)bhd * 1024 + s0 + ch * 8]) = v;
    }
  } else {
    // ---- Q/K epilogue: packed [bh][s][64]
    __bf16* dst = (seg == 0) ? Qp : Kp;
#pragma unroll
    for (int mt = 0; mt < 4; ++mt) {
      const int row0 = rowBase + waveM * 64 + mt * 16 + quad * 4;
#pragma unroll
      for (int nt = 0; nt < 4; ++nt) {
        const int col = colBase + waveN * 64 + nt * 16 + l16;
        const float bv = bias[col];
        const int cc = col & 1023;
#pragma unroll
        for (int r = 0; r < 4; ++r) {
          const int row = row0 + r;
          const float v = acc[mt][nt][r] + bv;
          const int bh = ((row >> 10) << 4) + (cc >> 6);
          dst[((size_t)bh << 16) + (size_t)(row & 1023) * 64 + (cc & 63)] =
              (__bf16)v;
        }
      }
    }
  }
}

// ---------------- GEMM2: out = A @ WT^T + bias, depth-2 pipelined ----------------
__global__ __launch_bounds__(256) void gemm_out(
    const __bf16* __restrict__ A, const __bf16* __restrict__ BT,
    const float* __restrict__ bias, float* __restrict__ C) {
  __shared__ __bf16 sA[3][128 * 32];  // 24 KB
  __shared__ __bf16 sB[3][128 * 32];  // 24 KB
  const int tid = threadIdx.x;
  const int lane = tid & 63;
  const int wave = tid >> 6;
  const int waveM = wave >> 1, waveN = wave & 1;
  const int quad = lane >> 4;
  const int l16 = lane & 15;
  const int rowBase = blockIdx.x * 128;
  const int colBase = blockIdx.y * 128;
  const int rIn = lane >> 2;
  const int sIn = lane & 3;
  const int gc = sIn ^ (rIn & 3) ^ ((rIn >> 2) & 3);
  const int readSlot = quad ^ (l16 & 3) ^ ((l16 >> 2) & 3);
  f32x4 acc[4][4] = {};

#define GO_STAGE(bi, k0_)                                                      \
  _Pragma("unroll") for (int j_ = 0; j_ < 2; ++j_) {                           \
    const int rb = wave * 32 + j_ * 16;                                        \
    load_lds16(&A[(size_t)(rowBase + rb + rIn) * 1024 + (k0_) + gc * 8],       \
               &sA[bi][rb * 32]);                                              \
    load_lds16(&BT[(size_t)(colBase + rb + rIn) * 1024 + (k0_) + gc * 8],      \
               &sB[bi][rb * 32]);                                              \
  }

  GO_STAGE(0, 0);
  GO_STAGE(1, 32);
  asm volatile("s_waitcnt vmcnt(4)" ::: "memory");  // tile 0 landed
  BAR8;

#pragma unroll
  for (int i = 0; i < 32; ++i) {
    if (i + 2 < 32) { GO_STAGE((i + 2) % 3, (i + 2) * 32); }
    const __bf16* sAc = sA[i % 3];
    const __bf16* sBc = sB[i % 3];
    bf16x8 af[4], bfr[4];
#pragma unroll
    for (int mt = 0; mt < 4; ++mt)
      af[mt] = *(const bf16x8*)(&sAc[(waveM * 64 + mt * 16 + l16) * 32 +
                                     readSlot * 8]);
#pragma unroll
    for (int nt = 0; nt < 4; ++nt)
      bfr[nt] = *(const bf16x8*)(&sBc[(waveN * 64 + nt * 16 + l16) * 32 +
                                      readSlot * 8]);
    __builtin_amdgcn_s_setprio(1);
#pragma unroll
    for (int mt = 0; mt < 4; ++mt)
#pragma unroll
      for (int nt = 0; nt < 4; ++nt)
        acc[mt][nt] = __builtin_amdgcn_mfma_f32_16x16x32_bf16(
            af[mt], bfr[nt], acc[mt][nt], 0, 0, 0);
    __builtin_amdgcn_s_setprio(0);
    if (i + 1 < 32) {
      if (i + 2 < 32) {
        asm volatile("s_waitcnt vmcnt(4)" ::: "memory");  // tile i+1 landed
      } else {
        asm volatile("s_waitcnt vmcnt(0)" ::: "memory");  // drain last stage
      }
      BAR8;
    }
  }

#pragma unroll
  for (int mt = 0; mt < 4; ++mt) {
    const int row = rowBase + waveM * 64 + mt * 16 + quad * 4;
#pragma unroll
    for (int nt = 0; nt < 4; ++nt) {
      const int col = colBase + waveN * 64 + nt * 16 + l16;
      const float bv = bias[col];
#pragma unroll
      for (int r = 0; r < 4; ++r)
        C[(size_t)(row + r) * 1024 + col] = acc[mt][nt][r] + bv;
    }
  }
}

// ---------------- flash attention (R19: paired tiles, 8-wave blocks) ----------
__global__ __launch_bounds__(512, 4) void attn_mfma(
    const __bf16* __restrict__ Qp, const __bf16* __restrict__ Kp,
    const __bf16* __restrict__ VT, __bf16* __restrict__ Aout) {
  __shared__ __bf16 sK[2][128 * 64];  // 32 KB
  __shared__ __bf16 sV[2][64 * 128];  // 32 KB
  __shared__ __bf16 sP[8 * 16 * 64];  // 16 KB, per-wave halved P

  const int tid = threadIdx.x;
  const int lane = tid & 63;
  const int wave = tid >> 6;       // 0..7
  const int wq = wave & 3;         // row-group within my tile
  const int tileSel = wave >> 2;   // 0 = long tile B, 1 = short tile A
  const int quad = lane >> 4;
  const int l16 = lane & 15;
  const int swq = l16 & 7;

  const int bh = blockIdx.x & 63;
  const int pr = blockIdx.x >> 6;  // 0..7
  const int b = bh >> 4, h = bh & 15;
  const int qbB = (15 - pr) * 64, qbA = pr * 64;
  const int ktB_max = (15 - pr) >> 1, ktA_max = pr >> 1;
  const int myQb = tileSel ? qbA : qbB;
  const int myKt = tileSel ? ktA_max : ktB_max;

  const __bf16* Qb = Qp + ((size_t)bh << 16);
  const __bf16* Kb = Kp + ((size_t)bh << 16);
  const __bf16* VTb = VT + (size_t)bh * 64 * 1024;

  bf16x8 qA0, qA1;
  {
    const __bf16* qr = Qb + (size_t)(myQb + wq * 16 + l16) * 64 + quad * 8;
    qA0 = *(const bf16x8*)qr;
    qA1 = *(const bf16x8*)(qr + 32);
  }

  f32x4 O[4] = {};
  float ps[4] = {0.f, 0.f, 0.f, 0.f};
  __bf16* pw = sP + wave * 1024;  // [16][64] per wave

#define ATTN_STAGE(bi, kbase)                                                  \
  _Pragma("unroll") for (int i_ = 0; i_ < 2; ++i_) {                           \
    const int rb = wave * 16 + i_ * 8;                                         \
    load_lds16(Kb + (size_t)((kbase) + rb + (lane >> 3)) * 64 +                \
                   (((lane & 7) ^ ((lane >> 3) & 7)) << 3),                    \
               &sK[bi][rb * 64]);                                              \
  }                                                                            \
  _Pragma("unroll") for (int i_ = 0; i_ < 2; ++i_) {                           \
    const int db = wave * 8 + i_ * 4;                                          \
    const int d = db + (lane >> 4);                                            \
    load_lds16(VTb + (size_t)d * 1024 + (kbase) +                              \
                   (((lane & 15) ^ (d & 7)) << 3),                             \
               &sV[bi][db * 128]);                                             \
  }

  ATTN_STAGE(0, 0);
  asm volatile("s_waitcnt vmcnt(0)" ::: "memory");
  BAR8;

  for (int kt = 0; kt <= ktB_max; ++kt) {
    const int kb = kt * 128;
    const int cur = kt & 1;
    if (kt < ktB_max) { ATTN_STAGE(cur ^ 1, kb + 128); }

    if (kt <= myKt) {  // wave-uniform
      const __bf16* skc = sK[cur];
      const __bf16* svc = sV[cur];

      float sc[8][4];
      __builtin_amdgcn_s_setprio(1);
#pragma unroll
      for (int n = 0; n < 8; ++n) {
        const int key = n * 16 + l16;
        bf16x8 kB0 = *(const bf16x8*)(&skc[key * 64 + ((quad ^ swq) << 3)]);
        bf16x8 kB1 = *(const bf16x8*)(&skc[key * 64 + (((quad + 4) ^ swq) << 3)]);
        f32x4 cacc = {};
        cacc = __builtin_amdgcn_mfma_f32_16x16x32_bf16(qA0, kB0, cacc, 0, 0, 0);
        cacc = __builtin_amdgcn_mfma_f32_16x16x32_bf16(qA1, kB1, cacc, 0, 0, 0);
#pragma unroll
        for (int r = 0; r < 4; ++r) sc[n][r] = cacc[r] * 0.125f;
      }
      __builtin_amdgcn_s_setprio(0);

      if (kt == myKt) {
#pragma unroll
        for (int n = 0; n < 8; ++n) {
          const int kg = kb + n * 16 + l16;
#pragma unroll
          for (int r = 0; r < 4; ++r)
            if (kg > myQb + wq * 16 + quad * 4 + r) sc[n][r] = -1.0e30f;
        }
      }

#pragma unroll
      for (int n = 0; n < 8; ++n)
#pragma unroll
        for (int r = 0; r < 4; ++r) {
          float p = __expf(fminf(sc[n][r], 60.0f));
          sc[n][r] = p;
          ps[r] += p;
        }

      const int kb8 = l16 >> 3, lo = l16 & 7;
#pragma unroll
      for (int hf = 0; hf < 2; ++hf) {
#pragma unroll
        for (int n = 4 * hf; n < 4 * hf + 4; ++n) {
          const int crel = (n - 4 * hf) * 2 + kb8;
#pragma unroll
          for (int r = 0; r < 4; ++r) {
            const int q = quad * 4 + r;
            pw[q * 64 + ((crel ^ (q & 7)) << 3) + lo] = (__bf16)sc[n][r];
          }
        }
        __builtin_amdgcn_s_setprio(1);
#pragma unroll
        for (int cc = 2 * hf; cc < 2 * hf + 2; ++cc) {
          const int crel = (cc - 2 * hf) * 4 + quad;
          bf16x8 pA = *(const bf16x8*)(&pw[l16 * 64 + ((crel ^ swq) << 3)]);
#pragma unroll
          for (int nt = 0; nt < 4; ++nt) {
            bf16x8 vB = *(const bf16x8*)(&svc[(nt * 16 + l16) * 128 +
                                              (((cc * 4 + quad) ^ swq) << 3)]);
            O[nt] = __builtin_amdgcn_mfma_f32_16x16x32_bf16(pA, vB, O[nt], 0, 0, 0);
          }
        }
        __builtin_amdgcn_s_setprio(0);
      }
    }

    if (kt < ktB_max) {
      asm volatile("s_waitcnt vmcnt(0)" ::: "memory");
      BAR8;
    }
  }

  // ---- epilogue
  float inv[4];
#pragma unroll
  for (int r = 0; r < 4; ++r) {
    float pa = ps[r];
    pa += __shfl_xor(pa, 1);
    pa += __shfl_xor(pa, 2);
    pa += __shfl_xor(pa, 4);
    pa += __shfl_xor(pa, 8);
    inv[r] = 1.0f / pa;
  }
#pragma unroll
  for (int nt = 0; nt < 4; ++nt) {
#pragma unroll
    for (int r = 0; r < 4; ++r) {
      const int q = myQb + wq * 16 + quad * 4 + r;
      Aout[((size_t)b * 1024 + q) * 1024 + h * 64 + nt * 16 + l16] =
          (__bf16)(O[nt][r] * inv[r]);
    }
  }
}

// ---------------- launch ----------------
extern "C" void kernel_launch(void* const* d_in, const int* in_sizes, int n_in,
                              void* d_out, int out_size, void* d_ws,
                              size_t ws_size, hipStream_t stream) {
  const float* x      = (const float*)d_in[0];
  const float* w_attn = (const float*)d_in[1];
  const float* b_attn = (const float*)d_in[2];
  const float* w_proj = (const float*)d_in[3];
  const float* b_proj = (const float*)d_in[4];
  float* out = (float*)d_out;

  char* ws = (char*)d_ws;
  __bf16* WT_attn = (__bf16*)(ws);                  //  6 MB
  __bf16* WT_proj = (__bf16*)(ws + 6291456);        //  2 MB
  __bf16* Xb      = (__bf16*)(ws + 8388608);        //  8 MB
  __bf16* Qp      = (__bf16*)(ws + 16777216);       //  8 MB [bh][s][64]
  __bf16* Kp      = (__bf16*)(ws + 25165824);       //  8 MB [bh][s][64]
  __bf16* VT      = (__bf16*)(ws + 33554432);       //  8 MB [bh][d][s]
  __bf16* Aattn   = (__bf16*)(ws + 41943040);       //  8 MB (end 50 MB)

  prep<<<5120, 256, 0, stream>>>(x, w_attn, w_proj, Xb, WT_attn, WT_proj);
  gemm_qkv<<<dim3(24, 32), 256, 0, stream>>>(Xb, WT_attn, b_attn, Qp, Kp, VT);
  attn_mfma<<<512, 512, 0, stream>>>(Qp, Kp, VT, Aattn);
  gemm_out<<<dim3(32, 8), 256, 0, stream>>>(Aattn, WT_proj, b_proj, out);
}